// Round 8
// baseline (374.190 us; speedup 1.0000x reference)
//
#include <hip/hip_runtime.h>
#include <math.h>

#define BB 32
#define NN 128
#define DD 64
#define EE 5
#define TT 6          // 1+T iterations
#define NE (NN*EE)    // 640
#define MSG_SZ ((size_t)BB*NN*EE*DD)   // 1310720
#define COL_SZ ((size_t)BB*NN*EE)      // 20480
#define PROP_SZ ((size_t)BB*NN*DD)     // 262144

__device__ __forceinline__ float fsig(float x) {
    float t = __expf(-x);
    return __fdividef(1.f, 1.f + t);
}
__device__ __forceinline__ float ftanh_(float x) {
    float xc = fminf(fmaxf(x, -15.f), 15.f);
    float t = __expf(-2.f * xc);
    return 1.f - __fdividef(2.f * t, 1.f + t);
}

// ===================== per-iteration kernel (2 rows/block) =====================
// k_iter<DO_B,DO_A>: PhaseB(t) (scores->out, merged, GRU) then PhaseA(t+1).
// Block owns 2 (b,i) rows; 256 threads (4 waves); grid = B*N/2 = 2048.
// Lane-quad decomposition in merged & Phase A: lane owns d-quad (f&15)*4,
// subrange (f>>4); float4 loads; shfl_xor(16,32) partial reduce.
template<int DO_B, int DO_A>
__global__ void __launch_bounds__(256, 8) k_iter(
    const float* __restrict__ propR, float* __restrict__ propW,
    const float* __restrict__ msgR, float* __restrict__ msgW,
    const float* __restrict__ colvR, float* __restrict__ colvW,
    const float* __restrict__ rowvR, float* __restrict__ rowvW,
    const int* __restrict__ mask,
    const float* __restrict__ We, const float* __restrict__ be,
    const float* __restrict__ Wa, const float* __restrict__ ba,
    const float* __restrict__ Wr, const float* __restrict__ br,
    const float* __restrict__ Wz, const float* __restrict__ bz,
    const float* __restrict__ Wh, const float* __restrict__ bh,
    float* __restrict__ out_t)
{
    // XCD-locality swizzle: batch b served by XCD b%8 (bid%8 assumption).
    const int bid = blockIdx.x;
    const int x = bid & 7;
    const int s = bid >> 3;
    const int b = x + 8 * (s >> 6);
    const int it = s & 63;
    const int bi0 = b * NN + it * 2;

    const int tid = threadIdx.x;
    const int g = tid >> 6;        // wave 0..3
    const int f = tid & 63;        // lane
    const int d = f;
    const int lq = f & 15;         // lane quad-id
    const int lg = f >> 4;         // lane group 0..3
    const int dq = lq * 4;         // d-quad base

    __shared__ float s_pt[DD][2];
    __shared__ float s_mt[DD][2];
    __shared__ float s_rpt[DD][2];
    __shared__ float s_sc[NE][2];
    __shared__ float s_part[4][2][DD];
    __shared__ float s_part2[4][2][DD];
    __shared__ float s_rv[2][EE];

    if (tid < 2 * DD) s_pt[f][g] = propR[(bi0 + g) * DD + f];
    if (DO_B && tid < 2 * EE) s_rv[tid / EE][tid % EE] = rowvR[bi0 * EE + tid];
    __syncthreads();

    if (DO_B) {
        // ---- scores -> out + LDS ----
        for (int je = tid; je < NE; je += 256) {
            const int j = je / EE, e = je - j * EE;
            const float cv = colvR[b * NE + je] + ba[e];
            #pragma unroll
            for (int qq = 0; qq < 2; ++qq) {
                float lg_ = s_rv[qq][e] + cv;
                float m = (float)mask[((size_t)(b * NN) + (it * 2) + qq) * NN + j];
                float sc = fsig(lg_) * m;
                s_sc[je][qq] = sc;
                out_t[(size_t)(bi0 + qq) * NE + je] = sc;
            }
        }
        __syncthreads();

        // ---- merged partials: wave g covers je in [g*160,+160), lane-quad ----
        {
            const float* mb = msgR + (size_t)b * NE * DD;
            float4 a0 = {0,0,0,0}, a1 = {0,0,0,0};
            const int je0 = g * 160;
            #pragma unroll 4
            for (int jb = 0; jb < 40; ++jb) {
                const int je = je0 + jb * 4 + lg;
                float4 m = *(const float4*)&mb[(size_t)je * DD + dq];
                float2 sc = *(const float2*)&s_sc[je][0];
                a0.x = fmaf(sc.x, m.x, a0.x); a0.y = fmaf(sc.x, m.y, a0.y);
                a0.z = fmaf(sc.x, m.z, a0.z); a0.w = fmaf(sc.x, m.w, a0.w);
                a1.x = fmaf(sc.y, m.x, a1.x); a1.y = fmaf(sc.y, m.y, a1.y);
                a1.z = fmaf(sc.y, m.z, a1.z); a1.w = fmaf(sc.y, m.w, a1.w);
            }
            #pragma unroll
            for (int off = 16; off <= 32; off <<= 1) {
                a0.x += __shfl_xor(a0.x, off); a0.y += __shfl_xor(a0.y, off);
                a0.z += __shfl_xor(a0.z, off); a0.w += __shfl_xor(a0.w, off);
                a1.x += __shfl_xor(a1.x, off); a1.y += __shfl_xor(a1.y, off);
                a1.z += __shfl_xor(a1.z, off); a1.w += __shfl_xor(a1.w, off);
            }
            if (lg == 0) {
                *(float4*)&s_part[g][0][dq] = a0;
                *(float4*)&s_part[g][1][dq] = a1;
            }
        }
        __syncthreads();

        // ---- combine merged (tid<128: q=g, d) ----
        float p_reg = 0.f, z_reg = 0.f;
        const int q = g;
        if (tid < 128) {
            float m_reg = s_part[0][q][d] + s_part[1][q][d]
                        + s_part[2][q][d] + s_part[3][q][d];
            p_reg = s_pt[d][q];
            s_mt[d][q] = m_reg;
        }
        __syncthreads();

        // ---- gates r,z: wave g covers a k-quarter ----
        {
            const float* vsrc = (g & 2) ? &s_pt[0][0] : &s_mt[0][0];
            const int kbase = (g & 2) ? 64 : 0;
            const int k0 = (g & 1) * 32;
            float r0=0,r1=0, z0=0,z1=0;
            #pragma unroll 8
            for (int kk = 0; kk < 32; ++kk) {
                int k = k0 + kk;
                int kg = kbase + k;
                float wr = Wr[kg * DD + d];
                float wz = Wz[kg * DD + d];
                float2 v = *(const float2*)&vsrc[k * 2];
                r0=fmaf(v.x,wr,r0); r1=fmaf(v.y,wr,r1);
                z0=fmaf(v.x,wz,z0); z1=fmaf(v.y,wz,z1);
            }
            s_part[g][0][d]=r0; s_part[g][1][d]=r1;
            s_part2[g][0][d]=z0; s_part2[g][1][d]=z1;
        }
        __syncthreads();

        if (tid < 128) {
            float ar = br[d] + s_part[0][q][d] + s_part[1][q][d] + s_part[2][q][d] + s_part[3][q][d];
            float az = bz[d] + s_part2[0][q][d] + s_part2[1][q][d] + s_part2[2][q][d] + s_part2[3][q][d];
            float r = fsig(ar);
            z_reg = fsig(az);
            s_rpt[d][q] = r * p_reg;
        }
        __syncthreads();

        // ---- gate h: same k-split over [merged | r*prop] ----
        {
            const float* vsrc = (g & 2) ? &s_rpt[0][0] : &s_mt[0][0];
            const int kbase = (g & 2) ? 64 : 0;
            const int k0 = (g & 1) * 32;
            float h0=0,h1=0;
            #pragma unroll 8
            for (int kk = 0; kk < 32; ++kk) {
                int k = k0 + kk;
                int kg = kbase + k;
                float wh = Wh[kg * DD + d];
                float2 v = *(const float2*)&vsrc[k * 2];
                h0=fmaf(v.x,wh,h0); h1=fmaf(v.y,wh,h1);
            }
            s_part[g][0][d]=h0; s_part[g][1][d]=h1;
        }
        __syncthreads();

        if (tid < 128) {
            float ah = bh[d] + s_part[0][q][d] + s_part[1][q][d] + s_part[2][q][d] + s_part[3][q][d];
            float hh = ftanh_(ah);
            float pn = (1.f - z_reg) * p_reg + z_reg * hh;
            s_pt[d][q] = pn;
            propW[(bi0 + q) * DD + d] = pn;
        }
        __syncthreads();
    }

    if (DO_A) {
        // ---- A1: wave g = expert e=g (lane-quad over f, k-sub over lg) ----
        {
            const int e = g;
            float4 a0 = {0,0,0,0}, a1 = {0,0,0,0};
            const int kg4 = lg * 16;
            #pragma unroll 4
            for (int kk = 0; kk < 16; ++kk) {
                const int k = kg4 + kk;
                float4 wv = *(const float4*)&We[((size_t)e * DD + k) * DD + dq];
                float2 p = *(const float2*)&s_pt[k][0];
                a0.x = fmaf(p.x, wv.x, a0.x); a0.y = fmaf(p.x, wv.y, a0.y);
                a0.z = fmaf(p.x, wv.z, a0.z); a0.w = fmaf(p.x, wv.w, a0.w);
                a1.x = fmaf(p.y, wv.x, a1.x); a1.y = fmaf(p.y, wv.y, a1.y);
                a1.z = fmaf(p.y, wv.z, a1.z); a1.w = fmaf(p.y, wv.w, a1.w);
            }
            #pragma unroll
            for (int off = 16; off <= 32; off <<= 1) {
                a0.x += __shfl_xor(a0.x, off); a0.y += __shfl_xor(a0.y, off);
                a0.z += __shfl_xor(a0.z, off); a0.w += __shfl_xor(a0.w, off);
                a1.x += __shfl_xor(a1.x, off); a1.y += __shfl_xor(a1.y, off);
                a1.z += __shfl_xor(a1.z, off); a1.w += __shfl_xor(a1.w, off);
            }
            if (lg == 0) {
                float4 bb = *(const float4*)&be[e * DD + dq];
                a0.x += bb.x; a0.y += bb.y; a0.z += bb.z; a0.w += bb.w;
                a1.x += bb.x; a1.y += bb.y; a1.z += bb.z; a1.w += bb.w;
                *(float4*)&msgW[((size_t)(bi0+0)*EE + e)*DD + dq] = a0;
                *(float4*)&msgW[((size_t)(bi0+1)*EE + e)*DD + dq] = a1;

                float4 war = *(const float4*)&Wa[e*2*DD + dq];
                float4 wac = *(const float4*)&Wa[e*2*DD + DD + dq];
                float r0 = a0.x*war.x + a0.y*war.y + a0.z*war.z + a0.w*war.w;
                float r1 = a1.x*war.x + a1.y*war.y + a1.z*war.z + a1.w*war.w;
                float c0 = a0.x*wac.x + a0.y*wac.y + a0.z*wac.z + a0.w*wac.w;
                float c1 = a1.x*wac.x + a1.y*wac.y + a1.z*wac.z + a1.w*wac.w;
                #pragma unroll
                for (int off = 1; off <= 8; off <<= 1) {
                    r0 += __shfl_xor(r0,off); r1 += __shfl_xor(r1,off);
                    c0 += __shfl_xor(c0,off); c1 += __shfl_xor(c1,off);
                }
                if (f == 0) {
                    rowvW[(bi0+0)*EE+e]=r0; rowvW[(bi0+1)*EE+e]=r1;
                    colvW[(bi0+0)*EE+e]=c0; colvW[(bi0+1)*EE+e]=c1;
                }
            }

            // e=4 partial: wave g covers k in [g*16,+16), lane-quad + lg k-sub
            float4 p0 = {0,0,0,0}, p1 = {0,0,0,0};
            const int kk0 = g * 16 + lg * 4;
            #pragma unroll
            for (int k = kk0; k < kk0 + 4; ++k) {
                float4 wv = *(const float4*)&We[((size_t)4 * DD + k) * DD + dq];
                float2 p = *(const float2*)&s_pt[k][0];
                p0.x = fmaf(p.x, wv.x, p0.x); p0.y = fmaf(p.x, wv.y, p0.y);
                p0.z = fmaf(p.x, wv.z, p0.z); p0.w = fmaf(p.x, wv.w, p0.w);
                p1.x = fmaf(p.y, wv.x, p1.x); p1.y = fmaf(p.y, wv.y, p1.y);
                p1.z = fmaf(p.y, wv.z, p1.z); p1.w = fmaf(p.y, wv.w, p1.w);
            }
            #pragma unroll
            for (int off = 16; off <= 32; off <<= 1) {
                p0.x += __shfl_xor(p0.x, off); p0.y += __shfl_xor(p0.y, off);
                p0.z += __shfl_xor(p0.z, off); p0.w += __shfl_xor(p0.w, off);
                p1.x += __shfl_xor(p1.x, off); p1.y += __shfl_xor(p1.y, off);
                p1.z += __shfl_xor(p1.z, off); p1.w += __shfl_xor(p1.w, off);
            }
            if (lg == 0) {
                *(float4*)&s_part[g][0][dq] = p0;
                *(float4*)&s_part[g][1][dq] = p1;
            }
        }
        __syncthreads();

        // ---- A2: combine e=4 (tid<128: q, f) ----
        if (tid < 128) {
            const int q = g;
            float m4 = be[4 * DD + f] + s_part[0][q][f] + s_part[1][q][f]
                                       + s_part[2][q][f] + s_part[3][q][f];
            msgW[((size_t)(bi0+q)*EE + 4)*DD + f] = m4;
            float pr = m4 * Wa[4*2*DD + f];
            float pc = m4 * Wa[4*2*DD + DD + f];
            #pragma unroll
            for (int off = 32; off; off >>= 1) {
                pr += __shfl_xor(pr, off);
                pc += __shfl_xor(pc, off);
            }
            if (f == 0) {
                rowvW[(bi0+q)*EE + 4] = pr;
                colvW[(bi0+q)*EE + 4] = pc;
            }
        }
    }
}

// ===================== fallback helper (round-2 proven) =====================
__global__ void __launch_bounds__(320) k_msg(
    const float* __restrict__ prop, const float* __restrict__ We,
    const float* __restrict__ be, const float* __restrict__ Wa,
    float* __restrict__ msg, float* __restrict__ rowv, float* __restrict__ colv)
{
    const int bn0 = blockIdx.x * 4;
    const int tid = threadIdx.x;
    const int e = tid >> 6, f = tid & 63;
    __shared__ float s_pt[DD][4];
    if (tid < 256) {
        int qq = tid >> 6, dd = tid & 63;
        s_pt[dd][qq] = prop[(bn0 + qq) * DD + dd];
    }
    __syncthreads();

    const float* w = We + e * DD * DD + f;
    const float bias = be[e * DD + f];
    float a0 = bias, a1 = bias, a2 = bias, a3 = bias;
    #pragma unroll 8
    for (int k = 0; k < DD; ++k) {
        float wv = w[k * DD];
        float4 p = *(const float4*)&s_pt[k][0];
        a0 = fmaf(p.x, wv, a0); a1 = fmaf(p.y, wv, a1);
        a2 = fmaf(p.z, wv, a2); a3 = fmaf(p.w, wv, a3);
    }
    msg[((size_t)(bn0+0)*EE + e)*DD + f] = a0;
    msg[((size_t)(bn0+1)*EE + e)*DD + f] = a1;
    msg[((size_t)(bn0+2)*EE + e)*DD + f] = a2;
    msg[((size_t)(bn0+3)*EE + e)*DD + f] = a3;

    const float war = Wa[e*2*DD + f], wac = Wa[e*2*DD + DD + f];
    float r0=a0*war, r1=a1*war, r2=a2*war, r3=a3*war;
    float c0=a0*wac, c1=a1*wac, c2=a2*wac, c3=a3*wac;
    #pragma unroll
    for (int off = 32; off; off >>= 1) {
        r0 += __shfl_xor(r0,off); r1 += __shfl_xor(r1,off);
        r2 += __shfl_xor(r2,off); r3 += __shfl_xor(r3,off);
        c0 += __shfl_xor(c0,off); c1 += __shfl_xor(c1,off);
        c2 += __shfl_xor(c2,off); c3 += __shfl_xor(c3,off);
    }
    if (f == 0) {
        rowv[(bn0+0)*EE+e]=r0; rowv[(bn0+1)*EE+e]=r1;
        rowv[(bn0+2)*EE+e]=r2; rowv[(bn0+3)*EE+e]=r3;
        colv[(bn0+0)*EE+e]=c0; colv[(bn0+1)*EE+e]=c1;
        colv[(bn0+2)*EE+e]=c2; colv[(bn0+3)*EE+e]=c3;
    }
}

extern "C" void kernel_launch(void* const* d_in, const int* in_sizes, int n_in,
                              void* d_out, int out_size, void* d_ws, size_t ws_size,
                              hipStream_t stream)
{
    const float* inputs = (const float*)d_in[0];
    const int*   mask   = (const int*)d_in[1];
    const float* We     = (const float*)d_in[2];
    const float* be     = (const float*)d_in[3];
    const float* Wa     = (const float*)d_in[4];
    const float* ba     = (const float*)d_in[5];
    const float* Wr     = (const float*)d_in[6];
    const float* br     = (const float*)d_in[7];
    const float* Wz     = (const float*)d_in[8];
    const float* bz     = (const float*)d_in[9];
    const float* Wh     = (const float*)d_in[10];
    const float* bh     = (const float*)d_in[11];
    float* out = (float*)d_out;
    float* ws = (float*)d_ws;

    const size_t need = (2*MSG_SZ + 3*COL_SZ + PROP_SZ) * sizeof(float);  // ~11.8 MB
    if (ws_size >= need) {
        float* msg0  = ws;
        float* msg1  = msg0 + MSG_SZ;
        float* colv0 = msg1 + MSG_SZ;
        float* colv1 = colv0 + COL_SZ;
        float* rowv  = colv1 + COL_SZ;
        float* prop  = rowv + COL_SZ;

        // prologue: PhaseA(0) only, prop source = inputs, writes msg(0)->buf0
        k_iter<0,1><<<BB*NN/2, 256, 0, stream>>>(
            inputs, prop, msg1, msg0, colv1, colv0, rowv, rowv, mask,
            We, be, Wa, ba, Wr, br, Wz, bz, Wh, bh, out);

        for (int t = 0; t < TT; ++t) {
            const float* msgR  = (t & 1) ? msg1 : msg0;
            float*       msgW  = (t & 1) ? msg0 : msg1;
            const float* colvR = (t & 1) ? colv1 : colv0;
            float*       colvW = (t & 1) ? colv0 : colv1;
            const float* propR = (t == 0) ? inputs : prop;
            float* out_t = out + (size_t)t * BB * NN * NE;
            if (t < TT - 1)
                k_iter<1,1><<<BB*NN/2, 256, 0, stream>>>(
                    propR, prop, msgR, msgW, colvR, colvW, rowv, rowv, mask,
                    We, be, Wa, ba, Wr, br, Wz, bz, Wh, bh, out_t);
            else
                k_iter<1,0><<<BB*NN/2, 256, 0, stream>>>(
                    propR, prop, msgR, msgW, colvR, colvW, rowv, rowv, mask,
                    We, be, Wa, ba, Wr, br, Wz, bz, Wh, bh, out_t);
        }
        return;
    }

    // ---- fallback: two-kernel path ----
    float* prop = ws;
    float* msg  = prop + PROP_SZ;
    float* rowv = msg + MSG_SZ;
    float* colv = rowv + COL_SZ;

    hipMemcpyAsync(prop, inputs, PROP_SZ * sizeof(float),
                   hipMemcpyDeviceToDevice, stream);

    for (int t = 0; t < TT; ++t) {
        k_msg<<<BB*NN/4, EE*DD, 0, stream>>>(prop, We, be, Wa, msg, rowv, colv);
        float* out_t = out + (size_t)t * BB * NN * NE;
        k_iter<1,0><<<BB*NN/2, 256, 0, stream>>>(
            prop, prop, msg, msg, colv, colv, rowv, rowv, mask,
            We, be, Wa, ba, Wr, br, Wz, bz, Wh, bh, out_t);
    }
}

// Round 9
// 302.287 us; speedup vs baseline: 1.2379x; 1.2379x over previous
//
#include <hip/hip_runtime.h>
#include <math.h>

#define BB 32
#define NN 128
#define DD 64
#define EE 5
#define TT 6          // 1+T iterations
#define NE (NN*EE)    // 640
#define MSG_SZ ((size_t)BB*NN*EE*DD)   // 1310720
#define COL_SZ ((size_t)BB*NN*EE)      // 20480
#define PROP_SZ ((size_t)BB*NN*DD)     // 262144
#define CNT_SLOTS (BB*8)               // 32 batches x 8 sync slots

__device__ __forceinline__ float fsig(float x) {
    float t = __expf(-x);
    return __fdividef(1.f, 1.f + t);
}
__device__ __forceinline__ float ftanh_(float x) {
    float xc = fminf(fmaxf(x, -15.f), 15.f);
    float t = __expf(-2.f * xc);
    return 1.f - __fdividef(2.f * t, 1.f + t);
}

#define SHFLR4(V, off) { V.x += __shfl_xor(V.x, off); V.y += __shfl_xor(V.y, off); \
                         V.z += __shfl_xor(V.z, off); V.w += __shfl_xor(V.w, off); }

// ===================== persistent kernel =====================
// One dispatch, TT iterations internal. Block owns 4 (b,i) rows; 256 thr;
// grid = 1024 (4 blocks/CU, co-residency checked on host). All 32 blocks of
// batch b live on XCD b%8 (validated by round-7 FETCH drop); per-batch sync
// via agent-scope atomic counters + acquire/release fences.
__global__ void __launch_bounds__(256) k_persist(
    const float* __restrict__ inputs, const int* __restrict__ mask,
    const float* __restrict__ We, const float* __restrict__ be,
    const float* __restrict__ Wa, const float* __restrict__ ba,
    const float* __restrict__ Wr, const float* __restrict__ br,
    const float* __restrict__ Wz, const float* __restrict__ bz,
    const float* __restrict__ Wh, const float* __restrict__ bh,
    float* __restrict__ out,
    float* __restrict__ msg0, float* __restrict__ msg1,
    float* __restrict__ colv0, float* __restrict__ colv1,
    unsigned int* __restrict__ cnt)
{
    const int bid = blockIdx.x;
    const int x = bid & 7;              // XCD (assumed bid%8)
    const int s = bid >> 3;             // 0..127 within XCD
    const int b = x + 8 * (s >> 5);     // 4 batches per XCD
    const int it = s & 31;              // i-tile (4 rows each)
    const int bi0 = b * NN + it * 4;

    const int tid = threadIdx.x;
    const int g = tid >> 6;        // wave 0..3
    const int f = tid & 63;        // lane
    const int d = f;
    const int lq = f & 15;         // lane quad id
    const int lg = f >> 4;         // lane group 0..3
    const int dq = lq * 4;         // d-quad base

    __shared__ float s_pt[DD][4];         // prop transposed [d][q]
    __shared__ float s_mt[DD][4];
    __shared__ float s_rpt[DD][4];
    __shared__ float s_sc[NE][4];
    __shared__ float s_part[4][4][DD];
    __shared__ float s_part2[4][4][DD];
    __shared__ float s_rv[4][EE];

    s_pt[f][g] = inputs[(bi0 + g) * DD + f];
    __syncthreads();

    // ---- Phase A: msg/rowv/colv for own 4 rows (wave g: experts g, g+4) ----
    auto phaseA = [&](float* msgW, float* colvW) {
        for (int e = g; e < EE; e += 4) {
            const float* w = We + e * DD * DD + f;
            const float bias = be[e * DD + f];
            float a0 = bias, a1 = bias, a2 = bias, a3 = bias;
            #pragma unroll 8
            for (int k = 0; k < DD; ++k) {
                float wv = w[k * DD];
                float4 p = *(const float4*)&s_pt[k][0];
                a0 = fmaf(p.x, wv, a0); a1 = fmaf(p.y, wv, a1);
                a2 = fmaf(p.z, wv, a2); a3 = fmaf(p.w, wv, a3);
            }
            msgW[((size_t)(bi0+0)*EE + e)*DD + f] = a0;
            msgW[((size_t)(bi0+1)*EE + e)*DD + f] = a1;
            msgW[((size_t)(bi0+2)*EE + e)*DD + f] = a2;
            msgW[((size_t)(bi0+3)*EE + e)*DD + f] = a3;

            const float war = Wa[e*2*DD + f], wac = Wa[e*2*DD + DD + f];
            float r0=a0*war, r1=a1*war, r2=a2*war, r3=a3*war;
            float c0=a0*wac, c1=a1*wac, c2=a2*wac, c3=a3*wac;
            #pragma unroll
            for (int off = 32; off; off >>= 1) {
                r0 += __shfl_xor(r0,off); r1 += __shfl_xor(r1,off);
                r2 += __shfl_xor(r2,off); r3 += __shfl_xor(r3,off);
                c0 += __shfl_xor(c0,off); c1 += __shfl_xor(c1,off);
                c2 += __shfl_xor(c2,off); c3 += __shfl_xor(c3,off);
            }
            if (f == 0) {
                s_rv[0][e]=r0; s_rv[1][e]=r1; s_rv[2][e]=r2; s_rv[3][e]=r3;
                colvW[(bi0+0)*EE+e]=c0; colvW[(bi0+1)*EE+e]=c1;
                colvW[(bi0+2)*EE+e]=c2; colvW[(bi0+3)*EE+e]=c3;
            }
        }
    };

    // ---- per-batch sync: all 32 blocks of batch b arrive at slot t ----
    auto batchSync = [&](int t) {
        __syncthreads();   // all threads' stores issued + vmcnt drained
        if (tid == 0) {
            __builtin_amdgcn_fence(__ATOMIC_RELEASE, "agent");
            __hip_atomic_fetch_add(&cnt[b * 8 + t], 1u,
                                   __ATOMIC_RELAXED, __HIP_MEMORY_SCOPE_AGENT);
            int n = 0;
            while (__hip_atomic_load(&cnt[b * 8 + t],
                                     __ATOMIC_RELAXED, __HIP_MEMORY_SCOPE_AGENT) < 32u
                   && ++n < (1 << 22)) {
                __builtin_amdgcn_s_sleep(1);
            }
            __builtin_amdgcn_fence(__ATOMIC_ACQUIRE, "agent");
        }
        __syncthreads();
    };

    phaseA(msg0, colv0);
    batchSync(0);

    for (int t = 0; t < TT; ++t) {
        const float* msgR  = (t & 1) ? msg1 : msg0;
        const float* colvR = (t & 1) ? colv1 : colv0;
        float* out_t = out + (size_t)t * BB * NN * NE;

        // ---- scores -> out + LDS ----
        for (int je = tid; je < NE; je += 256) {
            const int j = je / EE, e = je - j * EE;
            const float cv = colvR[b * NE + je] + ba[e];
            #pragma unroll
            for (int qq = 0; qq < 4; ++qq) {
                float lgt = s_rv[qq][e] + cv;
                float m = (float)mask[((size_t)(b * NN) + it * 4 + qq) * NN + j];
                float sc = fsig(lgt) * m;
                s_sc[je][qq] = sc;
                out_t[(size_t)(bi0 + qq) * NE + je] = sc;
            }
        }
        __syncthreads();

        // ---- merged partials: wave g covers je [g*160,+160), lane-quad ----
        {
            const float* mb = msgR + (size_t)b * NE * DD;
            float4 A0={0,0,0,0}, A1={0,0,0,0}, A2={0,0,0,0}, A3={0,0,0,0};
            const int je0 = g * 160;
            #pragma unroll 4
            for (int jb = 0; jb < 40; ++jb) {
                const int je = je0 + jb * 4 + lg;
                float4 m = *(const float4*)&mb[(size_t)je * DD + dq];
                float4 sc = *(const float4*)&s_sc[je][0];
                A0.x=fmaf(sc.x,m.x,A0.x); A0.y=fmaf(sc.x,m.y,A0.y);
                A0.z=fmaf(sc.x,m.z,A0.z); A0.w=fmaf(sc.x,m.w,A0.w);
                A1.x=fmaf(sc.y,m.x,A1.x); A1.y=fmaf(sc.y,m.y,A1.y);
                A1.z=fmaf(sc.y,m.z,A1.z); A1.w=fmaf(sc.y,m.w,A1.w);
                A2.x=fmaf(sc.z,m.x,A2.x); A2.y=fmaf(sc.z,m.y,A2.y);
                A2.z=fmaf(sc.z,m.z,A2.z); A2.w=fmaf(sc.z,m.w,A2.w);
                A3.x=fmaf(sc.w,m.x,A3.x); A3.y=fmaf(sc.w,m.y,A3.y);
                A3.z=fmaf(sc.w,m.z,A3.z); A3.w=fmaf(sc.w,m.w,A3.w);
            }
            SHFLR4(A0, 16) SHFLR4(A1, 16) SHFLR4(A2, 16) SHFLR4(A3, 16)
            SHFLR4(A0, 32) SHFLR4(A1, 32) SHFLR4(A2, 32) SHFLR4(A3, 32)
            if (lg == 0) {
                *(float4*)&s_part[g][0][dq] = A0;
                *(float4*)&s_part[g][1][dq] = A1;
                *(float4*)&s_part[g][2][dq] = A2;
                *(float4*)&s_part[g][3][dq] = A3;
            }
        }
        __syncthreads();

        // ---- combine merged (q = g) ----
        const int q = g;
        float p_reg, z_reg;
        {
            float m_reg = s_part[0][q][d] + s_part[1][q][d]
                        + s_part[2][q][d] + s_part[3][q][d];
            p_reg = s_pt[d][q];
            s_mt[d][q] = m_reg;
        }
        __syncthreads();

        // ---- gates r,z: wave g covers a k-quarter; weights read once/block ----
        {
            const float* vsrc = (g & 2) ? &s_pt[0][0] : &s_mt[0][0];
            const int kbase = (g & 2) ? 64 : 0;
            const int k0 = (g & 1) * 32;
            float r0=0,r1=0,r2=0,r3=0, z0=0,z1=0,z2=0,z3=0;
            #pragma unroll 8
            for (int kk = 0; kk < 32; ++kk) {
                int k = k0 + kk;
                int kg = kbase + k;
                float wr = Wr[kg * DD + d];
                float wz = Wz[kg * DD + d];
                float4 v = *(const float4*)&vsrc[k * 4];
                r0=fmaf(v.x,wr,r0); r1=fmaf(v.y,wr,r1); r2=fmaf(v.z,wr,r2); r3=fmaf(v.w,wr,r3);
                z0=fmaf(v.x,wz,z0); z1=fmaf(v.y,wz,z1); z2=fmaf(v.z,wz,z2); z3=fmaf(v.w,wz,z3);
            }
            s_part[g][0][d]=r0; s_part[g][1][d]=r1; s_part[g][2][d]=r2; s_part[g][3][d]=r3;
            s_part2[g][0][d]=z0; s_part2[g][1][d]=z1; s_part2[g][2][d]=z2; s_part2[g][3][d]=z3;
        }
        __syncthreads();

        {
            float ar = br[d] + s_part[0][q][d] + s_part[1][q][d] + s_part[2][q][d] + s_part[3][q][d];
            float az = bz[d] + s_part2[0][q][d] + s_part2[1][q][d] + s_part2[2][q][d] + s_part2[3][q][d];
            float r = fsig(ar);
            z_reg = fsig(az);
            s_rpt[d][q] = r * p_reg;
        }
        __syncthreads();

        // ---- gate h: same k-split over [merged | r*prop] ----
        {
            const float* vsrc = (g & 2) ? &s_rpt[0][0] : &s_mt[0][0];
            const int kbase = (g & 2) ? 64 : 0;
            const int k0 = (g & 1) * 32;
            float h0=0,h1=0,h2=0,h3=0;
            #pragma unroll 8
            for (int kk = 0; kk < 32; ++kk) {
                int k = k0 + kk;
                int kg = kbase + k;
                float wh = Wh[kg * DD + d];
                float4 v = *(const float4*)&vsrc[k * 4];
                h0=fmaf(v.x,wh,h0); h1=fmaf(v.y,wh,h1); h2=fmaf(v.z,wh,h2); h3=fmaf(v.w,wh,h3);
            }
            s_part[g][0][d]=h0; s_part[g][1][d]=h1; s_part[g][2][d]=h2; s_part[g][3][d]=h3;
        }
        __syncthreads();

        {
            float ah = bh[d] + s_part[0][q][d] + s_part[1][q][d] + s_part[2][q][d] + s_part[3][q][d];
            float hh = ftanh_(ah);
            float pn = (1.f - z_reg) * p_reg + z_reg * hh;
            s_pt[d][q] = pn;                 // prop stays in LDS
        }
        __syncthreads();

        if (t < TT - 1) {
            phaseA((t & 1) ? msg0 : msg1, (t & 1) ? colv0 : colv1);
            batchSync(t + 1);
        }
    }
}

// ===================== fallback: round-7 proven per-iteration kernel =====================
template<int DO_B, int DO_A>
__global__ void __launch_bounds__(256) k_iter(
    const float* __restrict__ propR, float* __restrict__ propW,
    const float* __restrict__ msgR, float* __restrict__ msgW,
    const float* __restrict__ colvR, float* __restrict__ colvW,
    const float* __restrict__ rowvR, float* __restrict__ rowvW,
    const int* __restrict__ mask,
    const float* __restrict__ We, const float* __restrict__ be,
    const float* __restrict__ Wa, const float* __restrict__ ba,
    const float* __restrict__ Wr, const float* __restrict__ br,
    const float* __restrict__ Wz, const float* __restrict__ bz,
    const float* __restrict__ Wh, const float* __restrict__ bh,
    float* __restrict__ out_t)
{
    const int bid = blockIdx.x;
    const int x = bid & 7;
    const int s = bid >> 3;
    const int b = x + 8 * (s >> 6);
    const int it = s & 63;
    const int bi0 = b * NN + it * 2;

    const int tid = threadIdx.x;
    const int g = tid >> 6;
    const int f = tid & 63;
    const int d = f;

    __shared__ float s_pt[DD][2];
    __shared__ float s_mt[DD][2];
    __shared__ float s_rpt[DD][2];
    __shared__ float s_sc[NE][2];
    __shared__ float s_part[4][2][DD];
    __shared__ float s_part2[4][2][DD];
    __shared__ float s_rv[2][EE];

    if (tid < 2 * DD) s_pt[f][g] = propR[(bi0 + g) * DD + f];
    if (DO_B && tid < 2 * EE) s_rv[tid / EE][tid % EE] = rowvR[bi0 * EE + tid];
    __syncthreads();

    if (DO_B) {
        for (int je = tid; je < NE; je += 256) {
            const int j = je / EE, e = je - j * EE;
            const float cv = colvR[b * NE + je] + ba[e];
            #pragma unroll
            for (int qq = 0; qq < 2; ++qq) {
                float lg_ = s_rv[qq][e] + cv;
                float m = (float)mask[((size_t)(b * NN) + (it * 2) + qq) * NN + j];
                float sc = fsig(lg_) * m;
                s_sc[je][qq] = sc;
                out_t[(size_t)(bi0 + qq) * NE + je] = sc;
            }
        }
        __syncthreads();

        {
            const float* mb = msgR + (size_t)b * NE * DD;
            float a0 = 0.f, a1 = 0.f;
            const int je0 = g * 160;
            #pragma unroll 8
            for (int je = je0; je < je0 + 160; ++je) {
                float m = mb[(size_t)je * DD + d];
                float2 sc = *(const float2*)&s_sc[je][0];
                a0 = fmaf(sc.x, m, a0); a1 = fmaf(sc.y, m, a1);
            }
            s_part[g][0][d] = a0; s_part[g][1][d] = a1;
        }
        __syncthreads();

        float p_reg = 0.f, z_reg = 0.f;
        const int q = g;
        if (tid < 128) {
            float m_reg = s_part[0][q][d] + s_part[1][q][d]
                        + s_part[2][q][d] + s_part[3][q][d];
            p_reg = s_pt[d][q];
            s_mt[d][q] = m_reg;
        }
        __syncthreads();

        {
            const float* vsrc = (g & 2) ? &s_pt[0][0] : &s_mt[0][0];
            const int kbase = (g & 2) ? 64 : 0;
            const int k0 = (g & 1) * 32;
            float r0=0,r1=0, z0=0,z1=0;
            #pragma unroll 8
            for (int kk = 0; kk < 32; ++kk) {
                int k = k0 + kk;
                int kg = kbase + k;
                float wr = Wr[kg * DD + d];
                float wz = Wz[kg * DD + d];
                float2 v = *(const float2*)&vsrc[k * 2];
                r0=fmaf(v.x,wr,r0); r1=fmaf(v.y,wr,r1);
                z0=fmaf(v.x,wz,z0); z1=fmaf(v.y,wz,z1);
            }
            s_part[g][0][d]=r0; s_part[g][1][d]=r1;
            s_part2[g][0][d]=z0; s_part2[g][1][d]=z1;
        }
        __syncthreads();

        if (tid < 128) {
            float ar = br[d] + s_part[0][q][d] + s_part[1][q][d] + s_part[2][q][d] + s_part[3][q][d];
            float az = bz[d] + s_part2[0][q][d] + s_part2[1][q][d] + s_part2[2][q][d] + s_part2[3][q][d];
            float r = fsig(ar);
            z_reg = fsig(az);
            s_rpt[d][q] = r * p_reg;
        }
        __syncthreads();

        {
            const float* vsrc = (g & 2) ? &s_rpt[0][0] : &s_mt[0][0];
            const int kbase = (g & 2) ? 64 : 0;
            const int k0 = (g & 1) * 32;
            float h0=0,h1=0;
            #pragma unroll 8
            for (int kk = 0; kk < 32; ++kk) {
                int k = k0 + kk;
                int kg = kbase + k;
                float wh = Wh[kg * DD + d];
                float2 v = *(const float2*)&vsrc[k * 2];
                h0=fmaf(v.x,wh,h0); h1=fmaf(v.y,wh,h1);
            }
            s_part[g][0][d]=h0; s_part[g][1][d]=h1;
        }
        __syncthreads();

        if (tid < 128) {
            float ah = bh[d] + s_part[0][q][d] + s_part[1][q][d] + s_part[2][q][d] + s_part[3][q][d];
            float hh = ftanh_(ah);
            float pn = (1.f - z_reg) * p_reg + z_reg * hh;
            s_pt[d][q] = pn;
            propW[(bi0 + q) * DD + d] = pn;
        }
        __syncthreads();
    }

    if (DO_A) {
        {
            const int e = g;
            const float* w = We + e * DD * DD + f;
            const float bias = be[e * DD + f];
            float a0 = bias, a1 = bias;
            #pragma unroll 8
            for (int k = 0; k < DD; ++k) {
                float wv = w[k * DD];
                float2 p = *(const float2*)&s_pt[k][0];
                a0 = fmaf(p.x, wv, a0); a1 = fmaf(p.y, wv, a1);
            }
            msgW[((size_t)(bi0+0)*EE + e)*DD + f] = a0;
            msgW[((size_t)(bi0+1)*EE + e)*DD + f] = a1;

            const float war = Wa[e*2*DD + f], wac = Wa[e*2*DD + DD + f];
            float r0=a0*war, r1=a1*war;
            float c0=a0*wac, c1=a1*wac;
            #pragma unroll
            for (int off = 32; off; off >>= 1) {
                r0 += __shfl_xor(r0,off); r1 += __shfl_xor(r1,off);
                c0 += __shfl_xor(c0,off); c1 += __shfl_xor(c1,off);
            }
            if (f == 0) {
                rowvW[(bi0+0)*EE+e]=r0; rowvW[(bi0+1)*EE+e]=r1;
                colvW[(bi0+0)*EE+e]=c0; colvW[(bi0+1)*EE+e]=c1;
            }

            const float* w4 = We + 4 * DD * DD + f;
            float pa0 = 0.f, pa1 = 0.f;
            const int kk0 = g * 16;
            #pragma unroll 8
            for (int k = kk0; k < kk0 + 16; ++k) {
                float wv = w4[k * DD];
                float2 p = *(const float2*)&s_pt[k][0];
                pa0 = fmaf(p.x, wv, pa0); pa1 = fmaf(p.y, wv, pa1);
            }
            s_part[g][0][f] = pa0; s_part[g][1][f] = pa1;
        }
        __syncthreads();

        if (tid < 128) {
            const int q = g;
            float m4 = be[4 * DD + f] + s_part[0][q][f] + s_part[1][q][f]
                                       + s_part[2][q][f] + s_part[3][q][f];
            msgW[((size_t)(bi0+q)*EE + 4)*DD + f] = m4;
            float pr = m4 * Wa[4*2*DD + f];
            float pc = m4 * Wa[4*2*DD + DD + f];
            #pragma unroll
            for (int off = 32; off; off >>= 1) {
                pr += __shfl_xor(pr, off);
                pc += __shfl_xor(pc, off);
            }
            if (f == 0) {
                rowvW[(bi0+q)*EE + 4] = pr;
                colvW[(bi0+q)*EE + 4] = pc;
            }
        }
    }
}

extern "C" void kernel_launch(void* const* d_in, const int* in_sizes, int n_in,
                              void* d_out, int out_size, void* d_ws, size_t ws_size,
                              hipStream_t stream)
{
    const float* inputs = (const float*)d_in[0];
    const int*   mask   = (const int*)d_in[1];
    const float* We     = (const float*)d_in[2];
    const float* be     = (const float*)d_in[3];
    const float* Wa     = (const float*)d_in[4];
    const float* ba     = (const float*)d_in[5];
    const float* Wr     = (const float*)d_in[6];
    const float* br     = (const float*)d_in[7];
    const float* Wz     = (const float*)d_in[8];
    const float* bz     = (const float*)d_in[9];
    const float* Wh     = (const float*)d_in[10];
    const float* bh     = (const float*)d_in[11];
    float* out = (float*)d_out;
    float* ws = (float*)d_ws;

    // layout: msg0 | msg1 | colv0 | colv1 | rowv | prop | cnt
    const size_t need = (2*MSG_SZ + 3*COL_SZ + PROP_SZ + CNT_SLOTS) * sizeof(float);
    if (ws_size >= need) {
        float* msg0  = ws;
        float* msg1  = msg0 + MSG_SZ;
        float* colv0 = msg1 + MSG_SZ;
        float* colv1 = colv0 + COL_SZ;
        float* rowv  = colv1 + COL_SZ;
        float* prop  = rowv + COL_SZ;
        unsigned int* cnt = (unsigned int*)(prop + PROP_SZ);

        int occ = 0;
        bool persist_ok =
            (hipOccupancyMaxActiveBlocksPerMultiprocessor(&occ, (const void*)k_persist,
                                                          256, 0) == hipSuccess)
            && occ >= 4;   // 4 blocks/CU x 256 CUs = 1024 co-resident

        if (persist_ok) {
            hipMemsetAsync(cnt, 0, CNT_SLOTS * sizeof(unsigned int), stream);
            k_persist<<<1024, 256, 0, stream>>>(
                inputs, mask, We, be, Wa, ba, Wr, br, Wz, bz, Wh, bh,
                out, msg0, msg1, colv0, colv1, cnt);
            return;
        }

        // round-7 proven multi-launch path
        k_iter<0,1><<<BB*NN/2, 256, 0, stream>>>(
            inputs, prop, msg1, msg0, colv1, colv0, rowv, rowv, mask,
            We, be, Wa, ba, Wr, br, Wz, bz, Wh, bh, out);
        for (int t = 0; t < TT; ++t) {
            const float* msgR  = (t & 1) ? msg1 : msg0;
            float*       msgW  = (t & 1) ? msg0 : msg1;
            const float* colvR = (t & 1) ? colv1 : colv0;
            float*       colvW = (t & 1) ? colv0 : colv1;
            const float* propR = (t == 0) ? inputs : prop;
            float* out_t = out + (size_t)t * BB * NN * NE;
            if (t < TT - 1)
                k_iter<1,1><<<BB*NN/2, 256, 0, stream>>>(
                    propR, prop, msgR, msgW, colvR, colvW, rowv, rowv, mask,
                    We, be, Wa, ba, Wr, br, Wz, bz, Wh, bh, out_t);
            else
                k_iter<1,0><<<BB*NN/2, 256, 0, stream>>>(
                    propR, prop, msgR, msgW, colvR, colvW, rowv, rowv, mask,
                    We, be, Wa, ba, Wr, br, Wz, bz, Wh, bh, out_t);
        }
        return;
    }

    // minimal-ws fallback: single-buffer round-7 structure (B then A each launch)
    float* prop = ws;
    float* msg  = prop + PROP_SZ;
    float* rowv = msg + MSG_SZ;
    float* colv = rowv + COL_SZ;
    k_iter<0,1><<<BB*NN/2, 256, 0, stream>>>(
        inputs, prop, msg, msg, colv, colv, rowv, rowv, mask,
        We, be, Wa, ba, Wr, br, Wz, bz, Wh, bh, out);
    for (int t = 0; t < TT; ++t) {
        const float* propR = (t == 0) ? inputs : prop;
        float* out_t = out + (size_t)t * BB * NN * NE;
        if (t < TT - 1)
            k_iter<1,1><<<BB*NN/2, 256, 0, stream>>>(
                propR, prop, msg, msg, colv, colv, rowv, rowv, mask,
                We, be, Wa, ba, Wr, br, Wz, bz, Wh, bh, out_t);
        else
            k_iter<1,0><<<BB*NN/2, 256, 0, stream>>>(
                propR, prop, msg, msg, colv, colv, rowv, rowv, mask,
                We, be, Wa, ba, Wr, br, Wz, bz, Wh, bh, out_t);
    }
}

// Round 10
// 295.342 us; speedup vs baseline: 1.2670x; 1.0235x over previous
//
#include <hip/hip_runtime.h>
#include <math.h>

#define BB 32
#define NN 128
#define DD 64
#define EE 5
#define TT 6          // 1+T iterations
#define NE (NN*EE)    // 640
#define MSG_SZ ((size_t)BB*NN*EE*DD)   // 1310720
#define COL_SZ ((size_t)BB*NN*EE)      // 20480
#define PROP_SZ ((size_t)BB*NN*DD)     // 262144

__device__ __forceinline__ float fsig(float x) {
    float t = __expf(-x);
    return __fdividef(1.f, 1.f + t);
}
__device__ __forceinline__ float ftanh_(float x) {
    float xc = fminf(fmaxf(x, -15.f), 15.f);
    float t = __expf(-2.f * xc);
    return 1.f - __fdividef(2.f * t, 1.f + t);
}

// ===================== per-iteration kernel (2 rows/block) =====================
// k_iter<DO_B,DO_A>: PhaseB(t) (scores->out, merged, GRU) then PhaseA(t+1).
// Block owns 2 (b,i) rows; 256 threads (4 waves); grid = B*N/2 = 2048.
// Lane-quad decomposition (merged, Phase A): lane owns d-quad (f&15)*4 and
// je/k-subrange (f>>4); float4 coalesced loads; shfl_xor(16,32) reduce.
// NO second launch_bounds arg: round-8 showed capping to 8 waves/EU forces
// VGPR=32 and spills (+78MB scratch traffic). Compiler lands <=64 naturally.
template<int DO_B, int DO_A>
__global__ void __launch_bounds__(256) k_iter(
    const float* __restrict__ propR, float* __restrict__ propW,
    const float* __restrict__ msgR, float* __restrict__ msgW,
    const float* __restrict__ colvR, float* __restrict__ colvW,
    const float* __restrict__ rowvR, float* __restrict__ rowvW,
    const int* __restrict__ mask,
    const float* __restrict__ We, const float* __restrict__ be,
    const float* __restrict__ Wa, const float* __restrict__ ba,
    const float* __restrict__ Wr, const float* __restrict__ br,
    const float* __restrict__ Wz, const float* __restrict__ bz,
    const float* __restrict__ Wh, const float* __restrict__ bh,
    float* __restrict__ out_t)
{
    // XCD-locality swizzle: batch b served by XCD b%8 (bid%8 assumption).
    const int bid = blockIdx.x;
    const int x = bid & 7;
    const int s = bid >> 3;
    const int b = x + 8 * (s >> 6);
    const int it = s & 63;
    const int bi0 = b * NN + it * 2;

    const int tid = threadIdx.x;
    const int g = tid >> 6;        // wave 0..3
    const int f = tid & 63;        // lane
    const int d = f;
    const int lq = f & 15;         // lane quad-id
    const int lg = f >> 4;         // lane group 0..3
    const int dq = lq * 4;         // d-quad base

    __shared__ float s_pt[DD][2];
    __shared__ float s_mt[DD][2];
    __shared__ float s_rpt[DD][2];
    __shared__ float s_sc[NE][2];
    __shared__ float s_part[4][2][DD];
    __shared__ float s_part2[4][2][DD];
    __shared__ float s_rv[2][EE];

    if (tid < 2 * DD) s_pt[f][g] = propR[(bi0 + g) * DD + f];
    if (DO_B && tid < 2 * EE) s_rv[tid / EE][tid % EE] = rowvR[bi0 * EE + tid];
    __syncthreads();

    if (DO_B) {
        // ---- scores -> out + LDS ----
        for (int je = tid; je < NE; je += 256) {
            const int j = je / EE, e = je - j * EE;
            const float cv = colvR[b * NE + je] + ba[e];
            #pragma unroll
            for (int qq = 0; qq < 2; ++qq) {
                float lg_ = s_rv[qq][e] + cv;
                float m = (float)mask[((size_t)(b * NN) + (it * 2) + qq) * NN + j];
                float sc = fsig(lg_) * m;
                s_sc[je][qq] = sc;
                out_t[(size_t)(bi0 + qq) * NE + je] = sc;
            }
        }
        __syncthreads();

        // ---- merged partials: wave g covers je [g*160,+160), lane-quad ----
        {
            const float* mb = msgR + (size_t)b * NE * DD;
            float4 a0 = {0,0,0,0}, a1 = {0,0,0,0};
            const int je0 = g * 160;
            #pragma unroll 4
            for (int jb = 0; jb < 40; ++jb) {
                const int je = je0 + jb * 4 + lg;
                float4 m = *(const float4*)&mb[(size_t)je * DD + dq];
                float2 sc = *(const float2*)&s_sc[je][0];
                a0.x = fmaf(sc.x, m.x, a0.x); a0.y = fmaf(sc.x, m.y, a0.y);
                a0.z = fmaf(sc.x, m.z, a0.z); a0.w = fmaf(sc.x, m.w, a0.w);
                a1.x = fmaf(sc.y, m.x, a1.x); a1.y = fmaf(sc.y, m.y, a1.y);
                a1.z = fmaf(sc.y, m.z, a1.z); a1.w = fmaf(sc.y, m.w, a1.w);
            }
            #pragma unroll
            for (int off = 16; off <= 32; off <<= 1) {
                a0.x += __shfl_xor(a0.x, off); a0.y += __shfl_xor(a0.y, off);
                a0.z += __shfl_xor(a0.z, off); a0.w += __shfl_xor(a0.w, off);
                a1.x += __shfl_xor(a1.x, off); a1.y += __shfl_xor(a1.y, off);
                a1.z += __shfl_xor(a1.z, off); a1.w += __shfl_xor(a1.w, off);
            }
            if (lg == 0) {
                *(float4*)&s_part[g][0][dq] = a0;
                *(float4*)&s_part[g][1][dq] = a1;
            }
        }
        __syncthreads();

        // ---- combine merged (tid<128: q=g, d) ----
        float p_reg = 0.f, z_reg = 0.f;
        const int q = g;
        if (tid < 128) {
            float m_reg = s_part[0][q][d] + s_part[1][q][d]
                        + s_part[2][q][d] + s_part[3][q][d];
            p_reg = s_pt[d][q];
            s_mt[d][q] = m_reg;
        }
        __syncthreads();

        // ---- gates r,z: wave g covers a k-quarter (round-7 proven) ----
        {
            const float* vsrc = (g & 2) ? &s_pt[0][0] : &s_mt[0][0];
            const int kbase = (g & 2) ? 64 : 0;
            const int k0 = (g & 1) * 32;
            float r0=0,r1=0, z0=0,z1=0;
            #pragma unroll 8
            for (int kk = 0; kk < 32; ++kk) {
                int k = k0 + kk;
                int kg = kbase + k;
                float wr = Wr[kg * DD + d];
                float wz = Wz[kg * DD + d];
                float2 v = *(const float2*)&vsrc[k * 2];
                r0=fmaf(v.x,wr,r0); r1=fmaf(v.y,wr,r1);
                z0=fmaf(v.x,wz,z0); z1=fmaf(v.y,wz,z1);
            }
            s_part[g][0][d]=r0; s_part[g][1][d]=r1;
            s_part2[g][0][d]=z0; s_part2[g][1][d]=z1;
        }
        __syncthreads();

        if (tid < 128) {
            float ar = br[d] + s_part[0][q][d] + s_part[1][q][d] + s_part[2][q][d] + s_part[3][q][d];
            float az = bz[d] + s_part2[0][q][d] + s_part2[1][q][d] + s_part2[2][q][d] + s_part2[3][q][d];
            float r = fsig(ar);
            z_reg = fsig(az);
            s_rpt[d][q] = r * p_reg;
        }
        __syncthreads();

        // ---- gate h: same k-split over [merged | r*prop] ----
        {
            const float* vsrc = (g & 2) ? &s_rpt[0][0] : &s_mt[0][0];
            const int kbase = (g & 2) ? 64 : 0;
            const int k0 = (g & 1) * 32;
            float h0=0,h1=0;
            #pragma unroll 8
            for (int kk = 0; kk < 32; ++kk) {
                int k = k0 + kk;
                int kg = kbase + k;
                float wh = Wh[kg * DD + d];
                float2 v = *(const float2*)&vsrc[k * 2];
                h0=fmaf(v.x,wh,h0); h1=fmaf(v.y,wh,h1);
            }
            s_part[g][0][d]=h0; s_part[g][1][d]=h1;
        }
        __syncthreads();

        if (tid < 128) {
            float ah = bh[d] + s_part[0][q][d] + s_part[1][q][d] + s_part[2][q][d] + s_part[3][q][d];
            float hh = ftanh_(ah);
            float pn = (1.f - z_reg) * p_reg + z_reg * hh;
            s_pt[d][q] = pn;
            propW[(bi0 + q) * DD + d] = pn;
        }
        __syncthreads();
    }

    if (DO_A) {
        // ---- A1: wave g = expert e=g (lane-quad over f, k-sub over lg) ----
        {
            const int e = g;
            float4 a0 = {0,0,0,0}, a1 = {0,0,0,0};
            const int kg4 = lg * 16;
            #pragma unroll 4
            for (int kk = 0; kk < 16; ++kk) {
                const int k = kg4 + kk;
                float4 wv = *(const float4*)&We[((size_t)e * DD + k) * DD + dq];
                float2 p = *(const float2*)&s_pt[k][0];
                a0.x = fmaf(p.x, wv.x, a0.x); a0.y = fmaf(p.x, wv.y, a0.y);
                a0.z = fmaf(p.x, wv.z, a0.z); a0.w = fmaf(p.x, wv.w, a0.w);
                a1.x = fmaf(p.y, wv.x, a1.x); a1.y = fmaf(p.y, wv.y, a1.y);
                a1.z = fmaf(p.y, wv.z, a1.z); a1.w = fmaf(p.y, wv.w, a1.w);
            }
            #pragma unroll
            for (int off = 16; off <= 32; off <<= 1) {
                a0.x += __shfl_xor(a0.x, off); a0.y += __shfl_xor(a0.y, off);
                a0.z += __shfl_xor(a0.z, off); a0.w += __shfl_xor(a0.w, off);
                a1.x += __shfl_xor(a1.x, off); a1.y += __shfl_xor(a1.y, off);
                a1.z += __shfl_xor(a1.z, off); a1.w += __shfl_xor(a1.w, off);
            }
            if (lg == 0) {
                float4 bb = *(const float4*)&be[e * DD + dq];
                a0.x += bb.x; a0.y += bb.y; a0.z += bb.z; a0.w += bb.w;
                a1.x += bb.x; a1.y += bb.y; a1.z += bb.z; a1.w += bb.w;
                *(float4*)&msgW[((size_t)(bi0+0)*EE + e)*DD + dq] = a0;
                *(float4*)&msgW[((size_t)(bi0+1)*EE + e)*DD + dq] = a1;

                float4 war = *(const float4*)&Wa[e*2*DD + dq];
                float4 wac = *(const float4*)&Wa[e*2*DD + DD + dq];
                float r0 = a0.x*war.x + a0.y*war.y + a0.z*war.z + a0.w*war.w;
                float r1 = a1.x*war.x + a1.y*war.y + a1.z*war.z + a1.w*war.w;
                float c0 = a0.x*wac.x + a0.y*wac.y + a0.z*wac.z + a0.w*wac.w;
                float c1 = a1.x*wac.x + a1.y*wac.y + a1.z*wac.z + a1.w*wac.w;
                #pragma unroll
                for (int off = 1; off <= 8; off <<= 1) {
                    r0 += __shfl_xor(r0,off); r1 += __shfl_xor(r1,off);
                    c0 += __shfl_xor(c0,off); c1 += __shfl_xor(c1,off);
                }
                if (f == 0) {
                    rowvW[(bi0+0)*EE+e]=r0; rowvW[(bi0+1)*EE+e]=r1;
                    colvW[(bi0+0)*EE+e]=c0; colvW[(bi0+1)*EE+e]=c1;
                }
            }

            // e=4 partial: wave g covers k in [g*16,+16), lane-quad + lg k-sub
            float4 p0 = {0,0,0,0}, p1 = {0,0,0,0};
            const int kk0 = g * 16 + lg * 4;
            #pragma unroll
            for (int k = kk0; k < kk0 + 4; ++k) {
                float4 wv = *(const float4*)&We[((size_t)4 * DD + k) * DD + dq];
                float2 p = *(const float2*)&s_pt[k][0];
                p0.x = fmaf(p.x, wv.x, p0.x); p0.y = fmaf(p.x, wv.y, p0.y);
                p0.z = fmaf(p.x, wv.z, p0.z); p0.w = fmaf(p.x, wv.w, p0.w);
                p1.x = fmaf(p.y, wv.x, p1.x); p1.y = fmaf(p.y, wv.y, p1.y);
                p1.z = fmaf(p.y, wv.z, p1.z); p1.w = fmaf(p.y, wv.w, p1.w);
            }
            #pragma unroll
            for (int off = 16; off <= 32; off <<= 1) {
                p0.x += __shfl_xor(p0.x, off); p0.y += __shfl_xor(p0.y, off);
                p0.z += __shfl_xor(p0.z, off); p0.w += __shfl_xor(p0.w, off);
                p1.x += __shfl_xor(p1.x, off); p1.y += __shfl_xor(p1.y, off);
                p1.z += __shfl_xor(p1.z, off); p1.w += __shfl_xor(p1.w, off);
            }
            if (lg == 0) {
                *(float4*)&s_part[g][0][dq] = p0;
                *(float4*)&s_part[g][1][dq] = p1;
            }
        }
        __syncthreads();

        // ---- A2: combine e=4 (tid<128: q, f) ----
        if (tid < 128) {
            const int q = g;
            float m4 = be[4 * DD + f] + s_part[0][q][f] + s_part[1][q][f]
                                       + s_part[2][q][f] + s_part[3][q][f];
            msgW[((size_t)(bi0+q)*EE + 4)*DD + f] = m4;
            float pr = m4 * Wa[4*2*DD + f];
            float pc = m4 * Wa[4*2*DD + DD + f];
            #pragma unroll
            for (int off = 32; off; off >>= 1) {
                pr += __shfl_xor(pr, off);
                pc += __shfl_xor(pc, off);
            }
            if (f == 0) {
                rowvW[(bi0+q)*EE + 4] = pr;
                colvW[(bi0+q)*EE + 4] = pc;
            }
        }
    }
}

extern "C" void kernel_launch(void* const* d_in, const int* in_sizes, int n_in,
                              void* d_out, int out_size, void* d_ws, size_t ws_size,
                              hipStream_t stream)
{
    const float* inputs = (const float*)d_in[0];
    const int*   mask   = (const int*)d_in[1];
    const float* We     = (const float*)d_in[2];
    const float* be     = (const float*)d_in[3];
    const float* Wa     = (const float*)d_in[4];
    const float* ba     = (const float*)d_in[5];
    const float* Wr     = (const float*)d_in[6];
    const float* br     = (const float*)d_in[7];
    const float* Wz     = (const float*)d_in[8];
    const float* bz     = (const float*)d_in[9];
    const float* Wh     = (const float*)d_in[10];
    const float* bh     = (const float*)d_in[11];
    float* out = (float*)d_out;
    float* ws = (float*)d_ws;

    const size_t need = (2*MSG_SZ + 3*COL_SZ + PROP_SZ) * sizeof(float);  // ~11.8 MB
    if (ws_size >= need) {
        float* msg0  = ws;
        float* msg1  = msg0 + MSG_SZ;
        float* colv0 = msg1 + MSG_SZ;
        float* colv1 = colv0 + COL_SZ;
        float* rowv  = colv1 + COL_SZ;
        float* prop  = rowv + COL_SZ;

        // prologue: PhaseA(0) only, prop source = inputs, writes msg(0)->buf0
        k_iter<0,1><<<BB*NN/2, 256, 0, stream>>>(
            inputs, prop, msg1, msg0, colv1, colv0, rowv, rowv, mask,
            We, be, Wa, ba, Wr, br, Wz, bz, Wh, bh, out);

        for (int t = 0; t < TT; ++t) {
            const float* msgR  = (t & 1) ? msg1 : msg0;
            float*       msgW  = (t & 1) ? msg0 : msg1;
            const float* colvR = (t & 1) ? colv1 : colv0;
            float*       colvW = (t & 1) ? colv0 : colv1;
            const float* propR = (t == 0) ? inputs : prop;
            float* out_t = out + (size_t)t * BB * NN * NE;
            if (t < TT - 1)
                k_iter<1,1><<<BB*NN/2, 256, 0, stream>>>(
                    propR, prop, msgR, msgW, colvR, colvW, rowv, rowv, mask,
                    We, be, Wa, ba, Wr, br, Wz, bz, Wh, bh, out_t);
            else
                k_iter<1,0><<<BB*NN/2, 256, 0, stream>>>(
                    propR, prop, msgR, msgW, colvR, colvW, rowv, rowv, mask,
                    We, be, Wa, ba, Wr, br, Wz, bz, Wh, bh, out_t);
        }
        return;
    }

    // ---- minimal-ws fallback: single-buffer (B then A each launch) ----
    float* prop = ws;
    float* msg  = prop + PROP_SZ;
    float* rowv = msg + MSG_SZ;
    float* colv = rowv + COL_SZ;
    k_iter<0,1><<<BB*NN/2, 256, 0, stream>>>(
        inputs, prop, msg, msg, colv, colv, rowv, rowv, mask,
        We, be, Wa, ba, Wr, br, Wz, bz, Wh, bh, out);
    for (int t = 0; t < TT; ++t) {
        const float* propR = (t == 0) ? inputs : prop;
        float* out_t = out + (size_t)t * BB * NN * NE;
        if (t < TT - 1)
            k_iter<1,1><<<BB*NN/2, 256, 0, stream>>>(
                propR, prop, msg, msg, colv, colv, rowv, rowv, mask,
                We, be, Wa, ba, Wr, br, Wz, bz, Wh, bh, out_t);
        else
            k_iter<1,0><<<BB*NN/2, 256, 0, stream>>>(
                propR, prop, msg, msg, colv, colv, rowv, rowv, mask,
                We, be, Wa, ba, Wr, br, Wz, bz, Wh, bh, out_t);
    }
}